// Round 11
// baseline (234.128 us; speedup 1.0000x reference)
//
#include <hip/hip_runtime.h>
#include <stdint.h>

#define B_ 2
#define S_ 2048
#define E_ 1024
#define H_ 16
#define D_ 64
#define M_ (B_*S_)
#define PROJ_ ((size_t)M_*E_)
#define HALF_W 128

typedef float    f32x4 __attribute__((ext_vector_type(4)));
typedef short    s16x4 __attribute__((ext_vector_type(4)));
typedef short    s16x8 __attribute__((ext_vector_type(8)));
typedef __bf16   bf16x8 __attribute__((ext_vector_type(8)));
typedef _Float16 f16x8 __attribute__((ext_vector_type(8)));
typedef unsigned int u32x4 __attribute__((ext_vector_type(4)));

typedef const __attribute__((address_space(1))) void* gas_t;
typedef __attribute__((address_space(3))) void*       las_t;

__device__ __forceinline__ void gl16(const void* g, void* l) {
    __builtin_amdgcn_global_load_lds((gas_t)g, (las_t)l, 16, 0, 0);
}

__device__ __forceinline__ f32x4 MFMA(bf16x8 a, bf16x8 b, f32x4 c) {
    return __builtin_amdgcn_mfma_f32_16x16x32_bf16(a, b, c, 0, 0, 0);
}
__device__ __forceinline__ f32x4 MFMAH(f16x8 a, f16x8 b, f32x4 c) {
    return __builtin_amdgcn_mfma_f32_16x16x32_f16(a, b, c, 0, 0, 0);
}

// raw v_exp_f32 — bypasses __ocml_exp2_f32's fixup path (args bounded here)
__device__ __forceinline__ float fexp2(float x) {
    return __builtin_amdgcn_exp2f(x);
}

__device__ __forceinline__ unsigned short f2bf(float f) {
    union { float f; unsigned int u; } x; x.f = f;
    unsigned int u = x.u + 0x7FFFu + ((x.u >> 16) & 1u);
    return (unsigned short)(u >> 16);
}

__device__ __forceinline__ s16x8 cvt8(f32x4 a, f32x4 b) {
    s16x8 h;
    h[0]=(short)f2bf(a[0]); h[1]=(short)f2bf(a[1]); h[2]=(short)f2bf(a[2]); h[3]=(short)f2bf(a[3]);
    h[4]=(short)f2bf(b[0]); h[5]=(short)f2bf(b[1]); h[6]=(short)f2bf(b[2]); h[7]=(short)f2bf(b[3]);
    return h;
}

// ---------------------------------------------------------------------------
// Kernel 0: fp32 -> bf16 converts (X inputs; W matrices when ws allows).
// ---------------------------------------------------------------------------
__global__ __launch_bounds__(256) void cvt_kernel(
    const float* __restrict__ q, const float* __restrict__ k, const float* __restrict__ v,
    const float* __restrict__ Wq, const float* __restrict__ Wk,
    const float* __restrict__ Wv, const float* __restrict__ Wo,
    unsigned short* __restrict__ xq, unsigned short* __restrict__ xk,
    unsigned short* __restrict__ xv, unsigned short* __restrict__ wbf)
{
    const int z = blockIdx.y;
    if (z >= 3 && blockIdx.x >= 512) return;
    const float* src; unsigned short* dst;
    switch (z) {
        case 0: src = q;  dst = xq; break;
        case 1: src = k;  dst = xk; break;
        case 2: src = v;  dst = xv; break;
        case 3: src = Wq; dst = wbf; break;
        case 4: src = Wk; dst = wbf + (size_t)E_*E_; break;
        case 5: src = Wv; dst = wbf + 2*(size_t)E_*E_; break;
        default: src = Wo; dst = wbf + 3*(size_t)E_*E_; break;
    }
    size_t i = ((size_t)blockIdx.x * 256 + threadIdx.x) * 8;
    f32x4 a = *(const f32x4*)(src + i);
    f32x4 c = *(const f32x4*)(src + i + 4);
    *(s16x8*)(dst + i) = cvt8(a, c);
}

// ---------------------------------------------------------------------------
// Kernel 1: QKV projections. 64(s) x 128(o) tile, BK=32, LDS dbuf async
// staging. grid=(8,64,3) = 1536 blocks -> 5 blocks/CU (occupancy up from 3).
// A=W rows (o on C-row -> vector stores), B=X rows. K pre-scaled by
// 0.125*log2(e); V stored f16 in blocked (bh,kb,d,slot) layout.
// ---------------------------------------------------------------------------
__global__ __launch_bounds__(256, 5) void qkv_kernel(
    const unsigned short* __restrict__ xq, const unsigned short* __restrict__ xk,
    const unsigned short* __restrict__ xv,
    const unsigned short* __restrict__ wbf,
    const float* __restrict__ Wq, const float* __restrict__ Wk, const float* __restrict__ Wv,
    const float* __restrict__ bq, const float* __restrict__ bk, const float* __restrict__ bv,
    unsigned short* __restrict__ qkvout)
{
    const int z = blockIdx.z;
    const unsigned short* X  = (z==0) ? xq : (z==1) ? xk : xv;
    const float*          Wf = (z==0) ? Wq : (z==1) ? Wk : Wv;
    const float*        bias = (z==0) ? bq : (z==1) ? bk : bv;
    const unsigned short* Wb = wbf ? (wbf + (size_t)z * E_ * E_) : nullptr;
    unsigned short* dst = qkvout + (size_t)z * PROJ_;

    __shared__ __align__(16) unsigned short Ws[2][128 * 32];   // W tile (o x k)
    __shared__ __align__(16) unsigned short Xs[2][64 * 32];    // X tile (s x k)

    const int t = threadIdx.x;
    const int lane = t & 63, w = t >> 6;
    const int quad = lane >> 4, l16 = lane & 15;
    const int wo2 = (w >> 1) * 64;    // o offset within 128
    const int ws2 = (w & 1) * 32;     // s offset within 64
    const int oBase = blockIdx.x * 128, sBase = blockIdx.y * 64;

    const int r0 = t >> 2;
    const int c4 = (t & 3) ^ (r0 & 3);
    const unsigned short* gX  = X + (size_t)(sBase + r0) * E_ + c4 * 8;
    const unsigned short* gWb = Wb ? Wb + (size_t)(oBase + r0) * E_ + c4 * 8 : nullptr;
    const float*          gWf = Wf + (size_t)(oBase + r0) * E_ + c4 * 8;

    f32x4 acc[4][2] = {};   // [io][is]

    auto issue = [&](int kk, int pb) {
        gl16(gX + kk, &Xs[pb][(size_t)w * 512]);
        if (gWb) {
            unsigned short* dW = &Ws[pb][(size_t)w * 512];
            gl16(gWb + kk, dW);
            gl16(gWb + (size_t)64 * E_ + kk, dW + 2048);
        } else {
            const float* gp0 = gWf + kk;
            const float* gp1 = gWf + (size_t)64 * E_ + kk;
            f32x4 a0 = *(const f32x4*)gp0, a1 = *(const f32x4*)(gp0 + 4);
            f32x4 b0 = *(const f32x4*)gp1, b1 = *(const f32x4*)(gp1 + 4);
            *(s16x8*)&Ws[pb][(size_t)r0 * 32 + (t & 3) * 8]        = cvt8(a0, a1);
            *(s16x8*)&Ws[pb][(size_t)(r0 + 64) * 32 + (t & 3) * 8] = cvt8(b0, b1);
        }
    };

    issue(0, 0);
    __syncthreads();

    for (int s = 0; s < 32; s++) {
        const int pb = s & 1;
        if (s < 31) issue((s + 1) * 32, pb ^ 1);

        bf16x8 af[4], bfr[2];
        #pragma unroll
        for (int io = 0; io < 4; io++) {
            int r = wo2 + io * 16 + l16;
            af[io] = *(const bf16x8*)&Ws[pb][(size_t)r * 32 + ((quad ^ (l16 & 3)) * 8)];
        }
        #pragma unroll
        for (int is = 0; is < 2; is++) {
            int r = ws2 + is * 16 + l16;
            bfr[is] = *(const bf16x8*)&Xs[pb][(size_t)r * 32 + ((quad ^ (l16 & 3)) * 8)];
        }
        #pragma unroll
        for (int io = 0; io < 4; io++)
            #pragma unroll
            for (int is = 0; is < 2; is++)
                acc[io][is] = MFMA(af[io], bfr[is], acc[io][is]);
        __syncthreads();
    }

    const float KSCL = 0.1803368801111204f;   // 0.125 * log2(e)
    #pragma unroll
    for (int is = 0; is < 2; is++) {
        int sg = sBase + ws2 + is * 16 + l16;     // b*S + s
        int b = sg >> 11, sg2 = sg & 2047;
        int k6 = sg2 & 63;
        int slot = ((k6 >> 5) & 1) * 32 + ((k6 >> 2) & 3) * 8
                 + ((k6 >> 4) & 1) * 4 + (k6 & 3);
        #pragma unroll
        for (int io = 0; io < 4; io++) {
            int ocol0 = oBase + wo2 + io * 16 + quad * 4;
            f32x4 bias4 = *(const f32x4*)&bias[ocol0];
            int h = ocol0 >> 6, d0 = ocol0 & 63;
            size_t base = ((size_t)(b * H_ + h)) * ((size_t)S_ * D_);
            if (z == 0) {
                s16x4 h4;
                #pragma unroll
                for (int r = 0; r < 4; r++) h4[r] = (short)f2bf(acc[io][is][r] + bias4[r]);
                *(s16x4*)&dst[base + (size_t)sg2 * D_ + d0] = h4;
            } else if (z == 1) {
                s16x4 h4;
                #pragma unroll
                for (int r = 0; r < 4; r++)
                    h4[r] = (short)f2bf((acc[io][is][r] + bias4[r]) * KSCL);
                *(s16x4*)&dst[base + (size_t)sg2 * D_ + d0] = h4;
            } else {
                size_t vb = base + (size_t)(sg2 >> 6) * 4096 + (size_t)d0 * 64 + slot;
                #pragma unroll
                for (int r = 0; r < 4; r++) {
                    _Float16 hv = (_Float16)(acc[io][is][r] + bias4[r]);
                    dst[vb + (size_t)r * 64] = __builtin_bit_cast(unsigned short, hv);
                }
            }
        }
    }
}

// ---------------------------------------------------------------------------
// Kernel 2: fused attention. grid=(32,32), block=256 (4 waves x 16 q).
// LDS dbuf, 1 barrier/tile (unroll-2 so pb is compile-time), tile-uniform
// mask classes with split accumulators, ones-MFMA denominator, f16 P/V,
// raw v_exp_f32.
// ---------------------------------------------------------------------------
__global__ __launch_bounds__(256, 4) void attn_kernel(
    const unsigned short* __restrict__ qkvout, unsigned short* __restrict__ attnout)
{
    const int bh = blockIdx.y, b = bh >> 4, h = bh & 15;
    const int qbase = blockIdx.x * 64;
    const int t = threadIdx.x, w = t >> 6, lane = t & 63;
    const int quad = lane >> 4, l16 = lane & 15;

    const unsigned short* qg = qkvout + (size_t)bh * (S_ * D_);
    const unsigned short* kg = qkvout + PROJ_ + (size_t)bh * (S_ * D_);
    const unsigned short* vT = qkvout + 2 * PROJ_ + (size_t)bh * (S_ * D_);

    __shared__ __align__(16) unsigned short Ks [2][64 * 64];
    __shared__ __align__(16) unsigned short VTs[2][64 * 64];

    const int qi = qbase + w * 16 + l16;
    bf16x8 aq0 = *(const bf16x8*)&qg[(size_t)qi * 64 + quad * 8];
    bf16x8 aq1 = *(const bf16x8*)&qg[(size_t)qi * 64 + 32 + quad * 8];

    f32x4 Oi[4] = {}, Oo[4] = {};
    f32x4 Si = {}, So = {};

    const int r0 = t >> 3;
    const int ch = ((t & 7) ^ (r0 & 7)) * 8;

    f16x8 onesv;
    #pragma unroll
    for (int j = 0; j < 8; j++) onesv[j] = (_Float16)1.0f;

    auto issue = [&](int kt, int pb) {
        unsigned short* dK = &Ks [pb][(size_t)w * 512];
        unsigned short* dV = &VTs[pb][(size_t)w * 512];
        gl16(kg + (size_t)(kt + r0) * 64 + ch,      dK);
        gl16(kg + (size_t)(kt + r0 + 32) * 64 + ch, dK + 2048);
        gl16(vT + (size_t)(kt + r0) * 64 + ch,      dV);
        gl16(vT + (size_t)(kt + r0 + 32) * 64 + ch, dV + 2048);
    };

    issue(0, 0);
    __syncthreads();

    #pragma unroll 2
    for (int s = 0; s < 32; s++) {
        const int pb = s & 1;
        const int kt = s * 64;
        if (s < 31) issue(kt + 64, pb ^ 1);

        const int dq = qbase - kt;
        const int adq = dq < 0 ? -dq : dq;
        const int cls = (adq <= 64) ? 0 : (adq >= 192 ? 1 : 2);

        f32x4 pp[4];
        const int sw = l16 & 7;
        #pragma unroll
        for (int sub = 0; sub < 4; sub++) {
            int row = sub * 16 + l16;
            bf16x8 bk0 = *(const bf16x8*)&Ks[pb][(size_t)row * 64 + ((quad ^ sw) * 8)];
            bf16x8 bk1 = *(const bf16x8*)&Ks[pb][(size_t)row * 64 + (((4 + quad) ^ sw) * 8)];
            f32x4 zz = {};
            zz = MFMA(bk0, aq0, zz);
            zz = MFMA(bk1, aq1, zz);
            if (cls == 2) {
                const int jb = kt + sub * 16 + quad * 4;
                #pragma unroll
                for (int r = 0; r < 4; r++) {
                    int di = qi - (jb + r); di = di < 0 ? -di : di;
                    pp[sub][r] = fexp2(zz[r] + (di <= HALF_W ? 0.f : 1.44269504089f));
                }
            } else {
                #pragma unroll
                for (int r = 0; r < 4; r++) pp[sub][r] = fexp2(zz[r]);
            }
        }

        u32x4 u0, u1;
        u0[0] = __builtin_bit_cast(unsigned int, __builtin_amdgcn_cvt_pkrtz(pp[0][0], pp[0][1]));
        u0[1] = __builtin_bit_cast(unsigned int, __builtin_amdgcn_cvt_pkrtz(pp[0][2], pp[0][3]));
        u0[2] = __builtin_bit_cast(unsigned int, __builtin_amdgcn_cvt_pkrtz(pp[1][0], pp[1][1]));
        u0[3] = __builtin_bit_cast(unsigned int, __builtin_amdgcn_cvt_pkrtz(pp[1][2], pp[1][3]));
        u1[0] = __builtin_bit_cast(unsigned int, __builtin_amdgcn_cvt_pkrtz(pp[2][0], pp[2][1]));
        u1[1] = __builtin_bit_cast(unsigned int, __builtin_amdgcn_cvt_pkrtz(pp[2][2], pp[2][3]));
        u1[2] = __builtin_bit_cast(unsigned int, __builtin_amdgcn_cvt_pkrtz(pp[3][0], pp[3][1]));
        u1[3] = __builtin_bit_cast(unsigned int, __builtin_amdgcn_cvt_pkrtz(pp[3][2], pp[3][3]));
        f16x8 aP0 = __builtin_bit_cast(f16x8, u0);
        f16x8 aP1 = __builtin_bit_cast(f16x8, u1);

        if (cls == 1) {
            #pragma unroll
            for (int dt = 0; dt < 4; dt++) {
                int row = dt * 16 + l16;
                f16x8 v0 = *(const f16x8*)&VTs[pb][(size_t)row * 64 + ((quad ^ sw) * 8)];
                f16x8 v1 = *(const f16x8*)&VTs[pb][(size_t)row * 64 + (((4 + quad) ^ sw) * 8)];
                Oo[dt] = MFMAH(aP0, v0, Oo[dt]);
                Oo[dt] = MFMAH(aP1, v1, Oo[dt]);
            }
            So = MFMAH(aP0, onesv, So);
            So = MFMAH(aP1, onesv, So);
        } else {
            #pragma unroll
            for (int dt = 0; dt < 4; dt++) {
                int row = dt * 16 + l16;
                f16x8 v0 = *(const f16x8*)&VTs[pb][(size_t)row * 64 + ((quad ^ sw) * 8)];
                f16x8 v1 = *(const f16x8*)&VTs[pb][(size_t)row * 64 + (((4 + quad) ^ sw) * 8)];
                Oi[dt] = MFMAH(aP0, v0, Oi[dt]);
                Oi[dt] = MFMAH(aP1, v1, Oi[dt]);
            }
            Si = MFMAH(aP0, onesv, Si);
            Si = MFMAH(aP1, onesv, Si);
        }
        __syncthreads();
    }

    const float E1 = 2.718281828459045f;
    float rd[4];
    #pragma unroll
    for (int r = 0; r < 4; r++) rd[r] = 1.0f / (Si[r] + E1 * So[r]);
    #pragma unroll
    for (int dt = 0; dt < 4; dt++)
        #pragma unroll
        for (int r = 0; r < 4; r++) {
            float oo = (Oi[dt][r] + E1 * Oo[dt][r]) * rd[r];
            int srow2 = qbase + w * 16 + quad * 4 + r;
            int col   = h * 64 + dt * 16 + l16;
            attnout[((size_t)(b * S_ + srow2)) * E_ + col] = f2bf(oo);
        }
}

// ---------------------------------------------------------------------------
// Kernel 3: output projection. 64x64 tile, BK=32, dbuf async staging.
// grid=(16,64) = 1024 blocks -> 4 blocks/CU. fp32 out.
// ---------------------------------------------------------------------------
__global__ __launch_bounds__(256, 4) void oproj_kernel(
    const unsigned short* __restrict__ Aattn, const unsigned short* __restrict__ WoBf,
    const float* __restrict__ Wo, const float* __restrict__ bo, float* __restrict__ out)
{
    __shared__ __align__(16) unsigned short As[2][64 * 32];
    __shared__ __align__(16) unsigned short Bs[2][64 * 32];

    const int t = threadIdx.x;
    const int lane = t & 63, w = t >> 6;
    const int quad = lane >> 4, l16 = lane & 15;
    const int wm = (w & 1) * 32, wn = (w >> 1) * 32;
    const int rowBase = blockIdx.y * 64, nBase = blockIdx.x * 64;

    const int r0 = t >> 2;
    const int c4 = (t & 3) ^ (r0 & 3);
    const unsigned short* gA  = Aattn + (size_t)(rowBase + r0) * E_ + c4 * 8;
    const unsigned short* gBb = WoBf ? WoBf + (size_t)(nBase + r0) * E_ + c4 * 8 : nullptr;
    const float*          gBf = Wo + (size_t)(nBase + r0) * E_ + c4 * 8;

    f32x4 acc[2][2] = {};

    auto issue = [&](int kk, int pb) {
        gl16(gA + kk, &As[pb][(size_t)w * 512]);
        if (gBb) {
            gl16(gBb + kk, &Bs[pb][(size_t)w * 512]);
        } else {
            const float* gp0 = gBf + kk;
            f32x4 a0 = *(const f32x4*)gp0, a1 = *(const f32x4*)(gp0 + 4);
            *(s16x8*)&Bs[pb][(size_t)r0 * 32 + (t & 3) * 8] = cvt8(a0, a1);
        }
    };

    issue(0, 0);
    __syncthreads();

    for (int s = 0; s < 32; s++) {
        const int pb = s & 1;
        if (s < 31) issue((s + 1) * 32, pb ^ 1);

        bf16x8 af[2], bfr[2];
        #pragma unroll
        for (int im = 0; im < 2; im++) {
            int r = wm + im * 16 + l16;
            af[im] = *(const bf16x8*)&As[pb][(size_t)r * 32 + ((quad ^ (l16 & 3)) * 8)];
        }
        #pragma unroll
        for (int in = 0; in < 2; in++) {
            int r = wn + in * 16 + l16;
            bfr[in] = *(const bf16x8*)&Bs[pb][(size_t)r * 32 + ((quad ^ (l16 & 3)) * 8)];
        }
        #pragma unroll
        for (int im = 0; im < 2; im++)
            #pragma unroll
            for (int in = 0; in < 2; in++)
                acc[im][in] = MFMA(af[im], bfr[in], acc[im][in]);
        __syncthreads();
    }

    #pragma unroll
    for (int im = 0; im < 2; im++)
      #pragma unroll
      for (int in = 0; in < 2; in++) {
          int col = nBase + wn + in * 16 + l16;
          float bb = bo[col];
          #pragma unroll
          for (int r = 0; r < 4; r++) {
              int row = rowBase + wm + im * 16 + quad * 4 + r;
              out[(size_t)row * E_ + col] = acc[im][in][r] + bb;
          }
      }
}

// ---------------------------------------------------------------------------
extern "C" void kernel_launch(void* const* d_in, const int* in_sizes, int n_in,
                              void* d_out, int out_size, void* d_ws, size_t ws_size,
                              hipStream_t stream) {
    const float* query = (const float*)d_in[0];
    const float* key_  = (const float*)d_in[1];
    const float* value = (const float*)d_in[2];
    const float* Wq = (const float*)d_in[3];
    const float* bq = (const float*)d_in[4];
    const float* Wk = (const float*)d_in[5];
    const float* bk = (const float*)d_in[6];
    const float* Wv = (const float*)d_in[7];
    const float* bv = (const float*)d_in[8];
    const float* Wo = (const float*)d_in[9];
    const float* bo = (const float*)d_in[10];

    unsigned short* ws      = (unsigned short*)d_ws;
    unsigned short* xv      = ws;                    // dead after qkv
    unsigned short* attnout = ws;                    // reuses xv region
    unsigned short* qkvout  = ws + PROJ_;            // 3*PROJ_
    size_t needW = (4 * PROJ_ + 4 * (size_t)E_ * E_) * 2;
    unsigned short* wbf = (ws_size >= needW) ? (ws + 4 * PROJ_) : nullptr;
    unsigned short* xq = (unsigned short*)d_out;     // scratch until oproj
    unsigned short* xk = xq + PROJ_;

    cvt_kernel<<<dim3(2048, wbf ? 7 : 3), 256, 0, stream>>>(
        query, key_, value, Wq, Wk, Wv, Wo, xq, xk, xv, wbf);
    qkv_kernel<<<dim3(8, 64, 3), 256, 0, stream>>>(
        xq, xk, xv, wbf, Wq, Wk, Wv, bq, bk, bv, qkvout);
    attn_kernel<<<dim3(32, 32), 256, 0, stream>>>(qkvout, attnout);
    oproj_kernel<<<dim3(16, 64), 256, 0, stream>>>(
        attnout, wbf ? wbf + 3 * (size_t)E_ * E_ : nullptr, Wo, bo, (float*)d_out);
}

// Round 12
// 218.520 us; speedup vs baseline: 1.0714x; 1.0714x over previous
//
#include <hip/hip_runtime.h>
#include <stdint.h>

#define B_ 2
#define S_ 2048
#define E_ 1024
#define H_ 16
#define D_ 64
#define M_ (B_*S_)
#define PROJ_ ((size_t)M_*E_)
#define HALF_W 128

typedef float    f32x4 __attribute__((ext_vector_type(4)));
typedef short    s16x4 __attribute__((ext_vector_type(4)));
typedef short    s16x8 __attribute__((ext_vector_type(8)));
typedef __bf16   bf16x8 __attribute__((ext_vector_type(8)));
typedef _Float16 f16x8 __attribute__((ext_vector_type(8)));
typedef unsigned int u32x4 __attribute__((ext_vector_type(4)));

typedef const __attribute__((address_space(1))) void* gas_t;
typedef __attribute__((address_space(3))) void*       las_t;

__device__ __forceinline__ void gl16(const void* g, void* l) {
    __builtin_amdgcn_global_load_lds((gas_t)g, (las_t)l, 16, 0, 0);
}

__device__ __forceinline__ f32x4 MFMA(bf16x8 a, bf16x8 b, f32x4 c) {
    return __builtin_amdgcn_mfma_f32_16x16x32_bf16(a, b, c, 0, 0, 0);
}
__device__ __forceinline__ f32x4 MFMAH(f16x8 a, f16x8 b, f32x4 c) {
    return __builtin_amdgcn_mfma_f32_16x16x32_f16(a, b, c, 0, 0, 0);
}

// raw v_exp_f32 — bypasses __ocml_exp2_f32's fixup path (args bounded here)
__device__ __forceinline__ float fexp2(float x) {
    return __builtin_amdgcn_exp2f(x);
}

__device__ __forceinline__ unsigned short f2bf(float f) {
    union { float f; unsigned int u; } x; x.f = f;
    unsigned int u = x.u + 0x7FFFu + ((x.u >> 16) & 1u);
    return (unsigned short)(u >> 16);
}

__device__ __forceinline__ s16x8 cvt8(f32x4 a, f32x4 b) {
    s16x8 h;
    h[0]=(short)f2bf(a[0]); h[1]=(short)f2bf(a[1]); h[2]=(short)f2bf(a[2]); h[3]=(short)f2bf(a[3]);
    h[4]=(short)f2bf(b[0]); h[5]=(short)f2bf(b[1]); h[6]=(short)f2bf(b[2]); h[7]=(short)f2bf(b[3]);
    return h;
}

// ---------------------------------------------------------------------------
// Kernel 0: fp32 -> bf16 converts (X inputs; W matrices when ws allows).
// ---------------------------------------------------------------------------
__global__ __launch_bounds__(256) void cvt_kernel(
    const float* __restrict__ q, const float* __restrict__ k, const float* __restrict__ v,
    const float* __restrict__ Wq, const float* __restrict__ Wk,
    const float* __restrict__ Wv, const float* __restrict__ Wo,
    unsigned short* __restrict__ xq, unsigned short* __restrict__ xk,
    unsigned short* __restrict__ xv, unsigned short* __restrict__ wbf)
{
    const int z = blockIdx.y;
    if (z >= 3 && blockIdx.x >= 512) return;
    const float* src; unsigned short* dst;
    switch (z) {
        case 0: src = q;  dst = xq; break;
        case 1: src = k;  dst = xk; break;
        case 2: src = v;  dst = xv; break;
        case 3: src = Wq; dst = wbf; break;
        case 4: src = Wk; dst = wbf + (size_t)E_*E_; break;
        case 5: src = Wv; dst = wbf + 2*(size_t)E_*E_; break;
        default: src = Wo; dst = wbf + 3*(size_t)E_*E_; break;
    }
    size_t i = ((size_t)blockIdx.x * 256 + threadIdx.x) * 8;
    f32x4 a = *(const f32x4*)(src + i);
    f32x4 c = *(const f32x4*)(src + i + 4);
    *(s16x8*)(dst + i) = cvt8(a, c);
}

// ---------------------------------------------------------------------------
// Kernel 1: QKV projections, operand-swapped (A=W rows, B=X rows).
// 128x128 tile, BK=32, LDS dbuf async staging, 1 barrier/step.
// K pre-scaled by 0.125*log2(e). V stored f16 in blocked (bh,kb,d,slot)
// layout. grid=(8,32,3), block=256.  (round-10 config: best measured)
// ---------------------------------------------------------------------------
__global__ __launch_bounds__(256, 3) void qkv_kernel(
    const unsigned short* __restrict__ xq, const unsigned short* __restrict__ xk,
    const unsigned short* __restrict__ xv,
    const unsigned short* __restrict__ wbf,
    const float* __restrict__ Wq, const float* __restrict__ Wk, const float* __restrict__ Wv,
    const float* __restrict__ bq, const float* __restrict__ bk, const float* __restrict__ bv,
    unsigned short* __restrict__ qkvout)
{
    const int z = blockIdx.z;
    const unsigned short* X  = (z==0) ? xq : (z==1) ? xk : xv;
    const float*          Wf = (z==0) ? Wq : (z==1) ? Wk : Wv;
    const float*        bias = (z==0) ? bq : (z==1) ? bk : bv;
    const unsigned short* Wb = wbf ? (wbf + (size_t)z * E_ * E_) : nullptr;
    unsigned short* dst = qkvout + (size_t)z * PROJ_;

    __shared__ __align__(16) unsigned short As[2][128 * 32];   // W tile
    __shared__ __align__(16) unsigned short Bs[2][128 * 32];   // X tile

    const int t = threadIdx.x;
    const int lane = t & 63, w = t >> 6;
    const int quad = lane >> 4, l16 = lane & 15;
    const int wo = (w & 1) * 64, wsb = (w >> 1) * 64;
    const int oBase = blockIdx.x * 128, sBase = blockIdx.y * 128;

    const int r0 = t >> 2;
    const int c4 = (t & 3) ^ (r0 & 3);
    const unsigned short* gX  = X + (size_t)(sBase + r0) * E_ + c4 * 8;
    const unsigned short* gWb = Wb ? Wb + (size_t)(oBase + r0) * E_ + c4 * 8 : nullptr;
    const float*          gWf = Wf + (size_t)(oBase + r0) * E_ + c4 * 8;

    f32x4 acc[4][4] = {};   // [io][is]

    auto issue = [&](int kk, int pb) {
        unsigned short* dB = &Bs[pb][(size_t)w * 512];
        gl16(gX + kk, dB);
        gl16(gX + (size_t)64 * E_ + kk, dB + 2048);
        if (gWb) {
            unsigned short* dA = &As[pb][(size_t)w * 512];
            gl16(gWb + kk, dA);
            gl16(gWb + (size_t)64 * E_ + kk, dA + 2048);
        } else {
            const float* gp0 = gWf + kk;
            const float* gp1 = gWf + (size_t)64 * E_ + kk;
            f32x4 a0 = *(const f32x4*)gp0, a1 = *(const f32x4*)(gp0 + 4);
            f32x4 b0 = *(const f32x4*)gp1, b1 = *(const f32x4*)(gp1 + 4);
            *(s16x8*)&As[pb][(size_t)r0 * 32 + (t & 3) * 8]        = cvt8(a0, a1);
            *(s16x8*)&As[pb][(size_t)(r0 + 64) * 32 + (t & 3) * 8] = cvt8(b0, b1);
        }
    };

    issue(0, 0);
    __syncthreads();

    for (int s = 0; s < 32; s++) {
        const int pb = s & 1;
        if (s < 31) issue((s + 1) * 32, pb ^ 1);

        bf16x8 af[4], bfr[4];
        #pragma unroll
        for (int io = 0; io < 4; io++) {
            int r = wo + io * 16 + l16;
            af[io] = *(const bf16x8*)&As[pb][(size_t)r * 32 + ((quad ^ (l16 & 3)) * 8)];
        }
        #pragma unroll
        for (int is = 0; is < 4; is++) {
            int r = wsb + is * 16 + l16;
            bfr[is] = *(const bf16x8*)&Bs[pb][(size_t)r * 32 + ((quad ^ (l16 & 3)) * 8)];
        }
        #pragma unroll
        for (int io = 0; io < 4; io++)
            #pragma unroll
            for (int is = 0; is < 4; is++)
                acc[io][is] = MFMA(af[io], bfr[is], acc[io][is]);
        __syncthreads();
    }

    const float KSCL = 0.1803368801111204f;   // 0.125 * log2(e)
    #pragma unroll
    for (int is = 0; is < 4; is++) {
        int sg = sBase + wsb + is * 16 + l16;     // b*S + s
        int b = sg >> 11, sg2 = sg & 2047;
        int k6 = sg2 & 63;
        int slot = ((k6 >> 5) & 1) * 32 + ((k6 >> 2) & 3) * 8
                 + ((k6 >> 4) & 1) * 4 + (k6 & 3);
        #pragma unroll
        for (int io = 0; io < 4; io++) {
            int ocol0 = oBase + wo + io * 16 + quad * 4;
            f32x4 bias4 = *(const f32x4*)&bias[ocol0];
            int h = ocol0 >> 6, d0 = ocol0 & 63;
            size_t base = ((size_t)(b * H_ + h)) * ((size_t)S_ * D_);
            if (z == 0) {
                s16x4 h4;
                #pragma unroll
                for (int r = 0; r < 4; r++) h4[r] = (short)f2bf(acc[io][is][r] + bias4[r]);
                *(s16x4*)&dst[base + (size_t)sg2 * D_ + d0] = h4;
            } else if (z == 1) {
                s16x4 h4;
                #pragma unroll
                for (int r = 0; r < 4; r++)
                    h4[r] = (short)f2bf((acc[io][is][r] + bias4[r]) * KSCL);
                *(s16x4*)&dst[base + (size_t)sg2 * D_ + d0] = h4;
            } else {
                size_t vb = base + (size_t)(sg2 >> 6) * 4096 + (size_t)d0 * 64 + slot;
                #pragma unroll
                for (int r = 0; r < 4; r++) {
                    _Float16 hv = (_Float16)(acc[io][is][r] + bias4[r]);
                    dst[vb + (size_t)r * 64] = __builtin_bit_cast(unsigned short, hv);
                }
            }
        }
    }
}

// ---------------------------------------------------------------------------
// Kernel 2: fused attention. grid=(32 bh, 32 qtile) — bh on x so XCD=bh%8:
// each XCD serves 4 heads -> K/V working set ~2MB fits its L2 (vs 16MB in
// L3 with qtile-major order). block=256 (4 waves x 16 q). LDS dbuf,
// 1 barrier/tile, tile-uniform mask classes, split accumulators, ones-MFMA
// denominator, f16 P/V, raw v_exp_f32.
// ---------------------------------------------------------------------------
__global__ __launch_bounds__(256, 4) void attn_kernel(
    const unsigned short* __restrict__ qkvout, unsigned short* __restrict__ attnout)
{
    const int bh = blockIdx.x, b = bh >> 4, h = bh & 15;
    const int qbase = blockIdx.y * 64;
    const int t = threadIdx.x, w = t >> 6, lane = t & 63;
    const int quad = lane >> 4, l16 = lane & 15;

    const unsigned short* qg = qkvout + (size_t)bh * (S_ * D_);
    const unsigned short* kg = qkvout + PROJ_ + (size_t)bh * (S_ * D_);
    const unsigned short* vT = qkvout + 2 * PROJ_ + (size_t)bh * (S_ * D_);

    __shared__ __align__(16) unsigned short Ks [2][64 * 64];
    __shared__ __align__(16) unsigned short VTs[2][64 * 64];

    const int qi = qbase + w * 16 + l16;
    bf16x8 aq0 = *(const bf16x8*)&qg[(size_t)qi * 64 + quad * 8];
    bf16x8 aq1 = *(const bf16x8*)&qg[(size_t)qi * 64 + 32 + quad * 8];

    f32x4 Oi[4] = {}, Oo[4] = {};
    f32x4 Si = {}, So = {};

    const int r0 = t >> 3;
    const int ch = ((t & 7) ^ (r0 & 7)) * 8;

    f16x8 onesv;
    #pragma unroll
    for (int j = 0; j < 8; j++) onesv[j] = (_Float16)1.0f;

    auto issue = [&](int kt, int pb) {
        unsigned short* dK = &Ks [pb][(size_t)w * 512];
        unsigned short* dV = &VTs[pb][(size_t)w * 512];
        gl16(kg + (size_t)(kt + r0) * 64 + ch,      dK);
        gl16(kg + (size_t)(kt + r0 + 32) * 64 + ch, dK + 2048);
        gl16(vT + (size_t)(kt + r0) * 64 + ch,      dV);
        gl16(vT + (size_t)(kt + r0 + 32) * 64 + ch, dV + 2048);
    };

    issue(0, 0);
    __syncthreads();

    #pragma unroll 2
    for (int s = 0; s < 32; s++) {
        const int pb = s & 1;
        const int kt = s * 64;
        if (s < 31) issue(kt + 64, pb ^ 1);

        const int dq = qbase - kt;
        const int adq = dq < 0 ? -dq : dq;
        const int cls = (adq <= 64) ? 0 : (adq >= 192 ? 1 : 2);

        f32x4 pp[4];
        const int sw = l16 & 7;
        #pragma unroll
        for (int sub = 0; sub < 4; sub++) {
            int row = sub * 16 + l16;
            bf16x8 bk0 = *(const bf16x8*)&Ks[pb][(size_t)row * 64 + ((quad ^ sw) * 8)];
            bf16x8 bk1 = *(const bf16x8*)&Ks[pb][(size_t)row * 64 + (((4 + quad) ^ sw) * 8)];
            f32x4 zz = {};
            zz = MFMA(bk0, aq0, zz);
            zz = MFMA(bk1, aq1, zz);
            if (cls == 2) {
                const int jb = kt + sub * 16 + quad * 4;
                #pragma unroll
                for (int r = 0; r < 4; r++) {
                    int di = qi - (jb + r); di = di < 0 ? -di : di;
                    pp[sub][r] = fexp2(zz[r] + (di <= HALF_W ? 0.f : 1.44269504089f));
                }
            } else {
                #pragma unroll
                for (int r = 0; r < 4; r++) pp[sub][r] = fexp2(zz[r]);
            }
        }

        u32x4 u0, u1;
        u0[0] = __builtin_bit_cast(unsigned int, __builtin_amdgcn_cvt_pkrtz(pp[0][0], pp[0][1]));
        u0[1] = __builtin_bit_cast(unsigned int, __builtin_amdgcn_cvt_pkrtz(pp[0][2], pp[0][3]));
        u0[2] = __builtin_bit_cast(unsigned int, __builtin_amdgcn_cvt_pkrtz(pp[1][0], pp[1][1]));
        u0[3] = __builtin_bit_cast(unsigned int, __builtin_amdgcn_cvt_pkrtz(pp[1][2], pp[1][3]));
        u1[0] = __builtin_bit_cast(unsigned int, __builtin_amdgcn_cvt_pkrtz(pp[2][0], pp[2][1]));
        u1[1] = __builtin_bit_cast(unsigned int, __builtin_amdgcn_cvt_pkrtz(pp[2][2], pp[2][3]));
        u1[2] = __builtin_bit_cast(unsigned int, __builtin_amdgcn_cvt_pkrtz(pp[3][0], pp[3][1]));
        u1[3] = __builtin_bit_cast(unsigned int, __builtin_amdgcn_cvt_pkrtz(pp[3][2], pp[3][3]));
        f16x8 aP0 = __builtin_bit_cast(f16x8, u0);
        f16x8 aP1 = __builtin_bit_cast(f16x8, u1);

        if (cls == 1) {
            #pragma unroll
            for (int dt = 0; dt < 4; dt++) {
                int row = dt * 16 + l16;
                f16x8 v0 = *(const f16x8*)&VTs[pb][(size_t)row * 64 + ((quad ^ sw) * 8)];
                f16x8 v1 = *(const f16x8*)&VTs[pb][(size_t)row * 64 + (((4 + quad) ^ sw) * 8)];
                Oo[dt] = MFMAH(aP0, v0, Oo[dt]);
                Oo[dt] = MFMAH(aP1, v1, Oo[dt]);
            }
            So = MFMAH(aP0, onesv, So);
            So = MFMAH(aP1, onesv, So);
        } else {
            #pragma unroll
            for (int dt = 0; dt < 4; dt++) {
                int row = dt * 16 + l16;
                f16x8 v0 = *(const f16x8*)&VTs[pb][(size_t)row * 64 + ((quad ^ sw) * 8)];
                f16x8 v1 = *(const f16x8*)&VTs[pb][(size_t)row * 64 + (((4 + quad) ^ sw) * 8)];
                Oi[dt] = MFMAH(aP0, v0, Oi[dt]);
                Oi[dt] = MFMAH(aP1, v1, Oi[dt]);
            }
            Si = MFMAH(aP0, onesv, Si);
            Si = MFMAH(aP1, onesv, Si);
        }
        __syncthreads();
    }

    const float E1 = 2.718281828459045f;
    float rd[4];
    #pragma unroll
    for (int r = 0; r < 4; r++) rd[r] = 1.0f / (Si[r] + E1 * So[r]);
    #pragma unroll
    for (int dt = 0; dt < 4; dt++)
        #pragma unroll
        for (int r = 0; r < 4; r++) {
            float oo = (Oi[dt][r] + E1 * Oo[dt][r]) * rd[r];
            int srow2 = qbase + w * 16 + quad * 4 + r;
            int col   = h * 64 + dt * 16 + l16;
            attnout[((size_t)(b * S_ + srow2)) * E_ + col] = f2bf(oo);
        }
}

// ---------------------------------------------------------------------------
// Kernel 3: output projection. 64x128 tile, BK=32, dbuf async staging.
// grid=(8,64), block=256, fp32 out.  (round-10 config)
// ---------------------------------------------------------------------------
__global__ __launch_bounds__(256, 2) void oproj_kernel(
    const unsigned short* __restrict__ Aattn, const unsigned short* __restrict__ WoBf,
    const float* __restrict__ Wo, const float* __restrict__ bo, float* __restrict__ out)
{
    __shared__ __align__(16) unsigned short As[2][64 * 32];
    __shared__ __align__(16) unsigned short Bs[2][128 * 32];

    const int t = threadIdx.x;
    const int lane = t & 63, w = t >> 6;
    const int quad = lane >> 4, l16 = lane & 15;
    const int wm = (w & 1) * 32, wn = (w >> 1) * 64;
    const int rowBase = blockIdx.y * 64, nBase = blockIdx.x * 128;

    const int r0 = t >> 2;
    const int c4 = (t & 3) ^ (r0 & 3);
    const unsigned short* gA  = Aattn + (size_t)(rowBase + r0) * E_ + c4 * 8;
    const unsigned short* gBb = WoBf ? WoBf + (size_t)(nBase + r0) * E_ + c4 * 8 : nullptr;
    const float*          gBf = Wo + (size_t)(nBase + r0) * E_ + c4 * 8;

    f32x4 acc[2][4] = {};

    auto issue = [&](int kk, int pb) {
        gl16(gA + kk, &As[pb][(size_t)w * 512]);
        if (gBb) {
            unsigned short* dB = &Bs[pb][(size_t)w * 512];
            gl16(gBb + kk, dB);
            gl16(gBb + (size_t)64 * E_ + kk, dB + 2048);
        } else {
            const float* gp0 = gBf + kk;
            const float* gp1 = gBf + (size_t)64 * E_ + kk;
            f32x4 a0 = *(const f32x4*)gp0, a1 = *(const f32x4*)(gp0 + 4);
            f32x4 b0 = *(const f32x4*)gp1, b1 = *(const f32x4*)(gp1 + 4);
            *(s16x8*)&Bs[pb][(size_t)r0 * 32 + (t & 3) * 8]        = cvt8(a0, a1);
            *(s16x8*)&Bs[pb][(size_t)(r0 + 64) * 32 + (t & 3) * 8] = cvt8(b0, b1);
        }
    };

    issue(0, 0);
    __syncthreads();

    for (int s = 0; s < 32; s++) {
        const int pb = s & 1;
        if (s < 31) issue((s + 1) * 32, pb ^ 1);

        bf16x8 af[2], bfr[4];
        #pragma unroll
        for (int im = 0; im < 2; im++) {
            int r = wm + im * 16 + l16;
            af[im] = *(const bf16x8*)&As[pb][(size_t)r * 32 + ((quad ^ (l16 & 3)) * 8)];
        }
        #pragma unroll
        for (int in = 0; in < 4; in++) {
            int r = wn + in * 16 + l16;
            bfr[in] = *(const bf16x8*)&Bs[pb][(size_t)r * 32 + ((quad ^ (l16 & 3)) * 8)];
        }
        #pragma unroll
        for (int im = 0; im < 2; im++)
            #pragma unroll
            for (int in = 0; in < 4; in++)
                acc[im][in] = MFMA(af[im], bfr[in], acc[im][in]);
        __syncthreads();
    }

    #pragma unroll
    for (int im = 0; im < 2; im++)
      #pragma unroll
      for (int in = 0; in < 4; in++) {
          int col = nBase + wn + in * 16 + l16;
          float bb = bo[col];
          #pragma unroll
          for (int r = 0; r < 4; r++) {
              int row = rowBase + wm + im * 16 + quad * 4 + r;
              out[(size_t)row * E_ + col] = acc[im][in][r] + bb;
          }
      }
}

// ---------------------------------------------------------------------------
extern "C" void kernel_launch(void* const* d_in, const int* in_sizes, int n_in,
                              void* d_out, int out_size, void* d_ws, size_t ws_size,
                              hipStream_t stream) {
    const float* query = (const float*)d_in[0];
    const float* key_  = (const float*)d_in[1];
    const float* value = (const float*)d_in[2];
    const float* Wq = (const float*)d_in[3];
    const float* bq = (const float*)d_in[4];
    const float* Wk = (const float*)d_in[5];
    const float* bk = (const float*)d_in[6];
    const float* Wv = (const float*)d_in[7];
    const float* bv = (const float*)d_in[8];
    const float* Wo = (const float*)d_in[9];
    const float* bo = (const float*)d_in[10];

    unsigned short* ws      = (unsigned short*)d_ws;
    unsigned short* xv      = ws;                    // dead after qkv
    unsigned short* attnout = ws;                    // reuses xv region
    unsigned short* qkvout  = ws + PROJ_;            // 3*PROJ_
    size_t needW = (4 * PROJ_ + 4 * (size_t)E_ * E_) * 2;
    unsigned short* wbf = (ws_size >= needW) ? (ws + 4 * PROJ_) : nullptr;
    unsigned short* xq = (unsigned short*)d_out;     // scratch until oproj
    unsigned short* xk = xq + PROJ_;

    cvt_kernel<<<dim3(2048, wbf ? 7 : 3), 256, 0, stream>>>(
        query, key_, value, Wq, Wk, Wv, Wo, xq, xk, xv, wbf);
    qkv_kernel<<<dim3(8, 32, 3), 256, 0, stream>>>(
        xq, xk, xv, wbf, Wq, Wk, Wv, bq, bk, bv, qkvout);
    attn_kernel<<<dim3(32, 32), 256, 0, stream>>>(qkvout, attnout);
    oproj_kernel<<<dim3(8, 64), 256, 0, stream>>>(
        attnout, wbf ? wbf + 3 * (size_t)E_ * E_ : nullptr, Wo, bo, (float*)d_out);
}